// Round 1
// baseline (381.878 us; speedup 1.0000x reference)
//
#include <hip/hip_runtime.h>
#include <stdint.h>

// Problem constants (from setup_inputs): B=8, H=256, W=256, C=16, HID=128, steps=2
#define BB 8
#define HH 256
#define WW 256
#define CC 16
#define HID 128
#define NPIX (BB*HH*WW)     // 524288
#define MTILE 64            // pixels per block
#define NBLK (NPIX/MTILE)   // 8192
#define DSTRIDE 20          // Dpart row stride in dwords (16 ch + 4 pad): all-32-bank b128

// ---------------- Threefry2x32 (JAX-compatible, 20 rounds) ----------------
// Verified against Random123 KAT: key=(0,0), ctr=(0,0) -> (0x6b200159, 0x99ba4efe).
__host__ __device__ __forceinline__ uint32_t rotl32(uint32_t x, int r) {
  return (x << r) | (x >> (32 - r));
}

__host__ __device__ inline void threefry2x32(uint32_t k0, uint32_t k1,
                                             uint32_t x0, uint32_t x1,
                                             uint32_t& o0, uint32_t& o1) {
  const uint32_t ks2 = k0 ^ k1 ^ 0x1BD11BDAu;
  x0 += k0; x1 += k1;
#define TF_R4(a,b,c,d) \
  x0 += x1; x1 = rotl32(x1,(a)); x1 ^= x0; \
  x0 += x1; x1 = rotl32(x1,(b)); x1 ^= x0; \
  x0 += x1; x1 = rotl32(x1,(c)); x1 ^= x0; \
  x0 += x1; x1 = rotl32(x1,(d)); x1 ^= x0;
  TF_R4(13,15,26,6)   x0 += k1;  x1 += ks2 + 1u;
  TF_R4(17,29,16,24)  x0 += ks2; x1 += k0 + 2u;
  TF_R4(13,15,26,6)   x0 += k0;  x1 += k1 + 3u;
  TF_R4(17,29,16,24)  x0 += k1;  x1 += ks2 + 4u;
  TF_R4(13,15,26,6)   x0 += ks2; x1 += k0 + 5u;
#undef TF_R4
  o0 = x0; o1 = x1;
}

// ---------------- Fused step kernel ----------------
// Block = 256 threads (4 waves), 64-pixel tile.
// Round-7 structure (round 6: 32 KB LDS, Occ 37%, VALUBusy 51% — latency-bound;
// H LDS round-trip + W1 vector loads were the footprint/idle drivers):
//  - GEMM1 wave-split over hidden: wave wid owns hid [wid*32,+32), lane = pixel,
//    W0/b0 via wave-uniform SCALAR loads (SMEM pipe).
//  - GEMM2 partials IN-REGISTER: dpart[c] = sum_s relu(acc[s])*W1[wid*32+s][c],
//    W1 also wave-uniform scalar loads. No Hs LDS round-trip, no W1 vector loads.
//  - Cross-wave reduce through Dpart[4][64][DSTRIDE=20] LDS (20 KB, union w/ Ys).
//    stride 20 -> b128 writes/reads hit all 32 banks (8 dwords/bank = minimal).
//  - LDS total 20480 B -> ~8 blocks/CU for latency hiding.
// NOTE: GEMM2's k-sum is reassociated ((w0+w1)+w2)+w3 vs sequential 0..127.
// Current absmax 0.0078 (values-only, fp32-vs-fp64) shows >=1e-5 margin at the
// 0.1 life threshold; reassociation shifts d by ~1e-7 -> safe.
__global__ __launch_bounds__(256, 4)
void step_fused(const float* __restrict__ xin,
                const float* __restrict__ W0g,
                const float* __restrict__ b0g,
                const float* __restrict__ W1g,
                float* __restrict__ xn,
                float* __restrict__ alpha_out,
                unsigned char* __restrict__ prelife,
                uint32_t k0, uint32_t k1) {
  __shared__ float Sh[80 * MTILE];   // 20480 B: Ys[80][64], then Dpart[4][64][20]

  const int t   = threadIdx.x;
  const int blk = blockIdx.x;

  // ---------------- perception: 4 channels per thread ----------------
  const int px  = t >> 2;        // 0..63 within tile
  const int c4  = (t & 3) * 4;   // channel quarter: 0,4,8,12
  const int gpx = blk * MTILE + px;
  const int bi  = gpx >> 16;     // H*W = 65536
  const int ij  = gpx & 0xFFFF;
  const int ic  = ij >> 8;
  const int jc  = ij & 0xFF;

  // 3x3 correlation weights (ANGLE=0: w1=dx, w2=dy), /8 pre-applied.
  // XLA conv_general_dilated is cross-correlation (no flip).
  const float DXW[3][3] = {{-0.125f, 0.0f, 0.125f},
                           {-0.25f,  0.0f, 0.25f },
                           {-0.125f, 0.0f, 0.125f}};
  const float DYW[3][3] = {{-0.125f, -0.25f, -0.125f},
                           { 0.0f,    0.0f,   0.0f  },
                           { 0.125f,  0.25f,  0.125f}};
  const float LPW[3][3] = {{0.125f, 0.25f, 0.125f},
                           {0.25f, -1.5f,  0.25f },
                           {0.125f, 0.25f, 0.125f}};
  const float L2W[3][3] = {{0.0f,   0.125f, 0.0f  },
                           {0.125f, -0.5f,  0.125f},
                           {0.0f,   0.125f, 0.0f  }};

  float ctr[4] = {0,0,0,0};
  float adx[4] = {0,0,0,0};
  float ady[4] = {0,0,0,0};
  float alp[4] = {0,0,0,0};
  float al2[4] = {0,0,0,0};
  float amax = 0.0f;

  const float* xb = xin + (size_t)bi * (HH * WW * CC);
#pragma unroll
  for (int di = -1; di <= 1; ++di) {
#pragma unroll
    for (int dj = -1; dj <= 1; ++dj) {
      const int ii = ic + di, jj = jc + dj;
      const bool ok = ((unsigned)ii < (unsigned)HH) && ((unsigned)jj < (unsigned)WW);
      float4 p = make_float4(0.f, 0.f, 0.f, 0.f);
      if (ok) p = *(const float4*)(xb + ((size_t)(ii * WW + jj) * CC + c4));
      const float wdx = DXW[di+1][dj+1], wdy = DYW[di+1][dj+1];
      const float wlp = LPW[di+1][dj+1], wl2 = L2W[di+1][dj+1];
      const float pv[4] = {p.x, p.y, p.z, p.w};
#pragma unroll
      for (int q = 0; q < 4; ++q) {
        if (di == 0 && dj == 0) ctr[q] = pv[q];
        if (wdx != 0.f) adx[q] = fmaf(pv[q], wdx, adx[q]);
        if (wdy != 0.f) ady[q] = fmaf(pv[q], wdy, ady[q]);
        if (wlp != 0.f) alp[q] = fmaf(pv[q], wlp, alp[q]);
        if (wl2 != 0.f) al2[q] = fmaf(pv[q], wl2, al2[q]);
      }
      if (c4 == 0) amax = fmaxf(amax, p.w);   // channel 3 lives in quarter 0
    }
  }
#pragma unroll
  for (int q = 0; q < 4; ++q) {
    Sh[(c4 + q) * MTILE + px]      = ctr[q];
    Sh[(16 + c4 + q) * MTILE + px] = adx[q];
    Sh[(32 + c4 + q) * MTILE + px] = ady[q];
    Sh[(48 + c4 + q) * MTILE + px] = alp[q];
    Sh[(64 + c4 + q) * MTILE + px] = al2[q];
  }
  if (c4 == 0) prelife[gpx] = (amax > 0.1f) ? 1 : 0;

  __syncthreads();

  // ------- GEMM1: h[hid][px] = relu(Y @ W0 + b0), wave-split over hidden ----
  const int lane = t & 63;
  const int wid  = __builtin_amdgcn_readfirstlane(t >> 6);   // 0..3, uniform
  const float* __restrict__ wslice = W0g + wid * 32;   // W0 row-major [80][128]
  const float* __restrict__ bslice = b0g + wid * 32;

  float acc[32];
#pragma unroll
  for (int s = 0; s < 32; ++s) acc[s] = bslice[s];     // scalar loads (uniform)

#pragma unroll 4
  for (int k = 0; k < 80; ++k) {
    const float yk = Sh[k * MTILE + lane];             // ds_read_b32, bank=lane
    const float* __restrict__ wr = wslice + k * HID;   // wave-uniform address
#pragma unroll
    for (int s = 0; s < 32; ++s) acc[s] = fmaf(wr[s], yk, acc[s]);  // sgpr fmac
  }

  // ------- GEMM2 partial, in-register: dpart[c] over this wave's 32 hid -----
  float dp[16];
#pragma unroll
  for (int c = 0; c < 16; ++c) dp[c] = 0.f;
#pragma unroll 4
  for (int s = 0; s < 32; ++s) {
    const float hr = fmaxf(acc[s], 0.f);
    const float* __restrict__ w1r = W1g + (wid * 32 + s) * CC;  // wave-uniform
#pragma unroll
    for (int c = 0; c < 16; ++c) dp[c] = fmaf(hr, w1r[c], dp[c]);  // sgpr fmac
  }

  __syncthreads();      // all Ys reads complete before Dpart overwrites union

  // Dpart[wid][px][DSTRIDE]: stride 20 dwords -> the 4 b128 writes per lane
  // cover all 32 banks (8 dwords/bank, minimal for full-wave b128).
  {
    float* drow = Sh + (wid * MTILE + lane) * DSTRIDE;
#pragma unroll
    for (int q = 0; q < 4; ++q)
      *(float4*)&drow[q * 4] = make_float4(dp[4*q], dp[4*q+1], dp[4*q+2], dp[4*q+3]);
  }
  __syncthreads();

  // ------- cross-wave reduce + stochastic update + store --------------------
  // Thread t: pixel px (= perception px), channels c4..c4+3 (= perception
  // quarter) -> x values are this thread's own ctr[0..3] registers.
  float4 dsum;
  {
    const float* base = Sh + px * DSTRIDE + c4;
    float4 p0 = *(const float4*)&base[0 * MTILE * DSTRIDE];
    float4 p1 = *(const float4*)&base[1 * MTILE * DSTRIDE];
    float4 p2 = *(const float4*)&base[2 * MTILE * DSTRIDE];
    float4 p3 = *(const float4*)&base[3 * MTILE * DSTRIDE];
    dsum.x = ((p0.x + p1.x) + p2.x) + p3.x;
    dsum.y = ((p0.y + p1.y) + p2.y) + p3.y;
    dsum.z = ((p0.z + p1.z) + p2.z) + p3.z;
    dsum.w = ((p0.w + p1.w) + p2.w) + p3.w;
  }

  // JAX uniform(key,(B,H,W,1)) > 0.5; jax_threefry_partitionable=True:
  // bits[i] = o0 ^ o1 of threefry(key, 0, i).
  uint32_t lo, hi;
  threefry2x32(k0, k1, 0u, (uint32_t)gpx, lo, hi);
  const uint32_t bits = lo ^ hi;
  const float u = __uint_as_float((bits >> 9) | 0x3f800000u) - 1.0f;
  const float fire01 = (u > 0.5f) ? 1.0f : 0.0f;

  const float xv0 = fmaf(dsum.x, fire01, ctr[0]);
  const float xv1 = fmaf(dsum.y, fire01, ctr[1]);
  const float xv2 = fmaf(dsum.z, fire01, ctr[2]);
  const float xv3 = fmaf(dsum.w, fire01, ctr[3]);

  // lane address = 4*t floats -> perfectly coalesced dwordx4 stores
  *(float4*)&xn[(size_t)gpx * CC + c4] = make_float4(xv0, xv1, xv2, xv3);
  if (c4 == 0) alpha_out[gpx] = xv3;   // channel 3
}

// ---------------- Kernel B: life mask ----------------
__global__ __launch_bounds__(256)
void life_mask(const float* __restrict__ xn,
               const float* __restrict__ alpha,
               const unsigned char* __restrict__ prelife,
               float* __restrict__ out) {
  const int idx = blockIdx.x * 256 + threadIdx.x;
  const int b  = idx >> 16;
  const int ij = idx & 0xFFFF;
  const int i  = ij >> 8;
  const int j  = ij & 0xFF;

  const float* ab = alpha + (size_t)b * (HH * WW);
  float amax = 0.0f;  // 0 for OOB is safe vs threshold 0.1
#pragma unroll
  for (int di = -1; di <= 1; ++di) {
    const int ii = i + di;
    if ((unsigned)ii >= (unsigned)HH) continue;
#pragma unroll
    for (int dj = -1; dj <= 1; ++dj) {
      const int jj = j + dj;
      if ((unsigned)jj >= (unsigned)WW) continue;
      amax = fmaxf(amax, ab[(size_t)ii * WW + jj]);
    }
  }
  const bool life = (prelife[idx] != 0) && (amax > 0.1f);

  const float4* src = (const float4*)(xn + (size_t)idx * CC);
  float4* dst = (float4*)(out + (size_t)idx * CC);
  if (life) {
    dst[0] = src[0]; dst[1] = src[1]; dst[2] = src[2]; dst[3] = src[3];
  } else {
    const float4 z = make_float4(0.0f, 0.0f, 0.0f, 0.0f);
    dst[0] = z; dst[1] = z; dst[2] = z; dst[3] = z;
  }
}

// ---------------- Host launcher ----------------
extern "C" void kernel_launch(void* const* d_in, const int* in_sizes, int n_in,
                              void* d_out, int out_size, void* d_ws, size_t ws_size,
                              hipStream_t stream) {
  (void)in_sizes; (void)n_in; (void)out_size; (void)ws_size;
  const float* x  = (const float*)d_in[0];
  const float* W0 = (const float*)d_in[1];
  const float* b0 = (const float*)d_in[2];
  const float* W1 = (const float*)d_in[3];
  float* out = (float*)d_out;

  // Workspace layout: xn state (32 MB) | alpha plane (2 MB) | prelife mask (0.5 MB)
  float* xn = (float*)d_ws;
  float* alpha = xn + (size_t)NPIX * CC;
  unsigned char* mask = (unsigned char*)(alpha + NPIX);

  const int steps = 2;
  for (int s = 0; s < steps; ++s) {
    // folded key = threefry2x32(seed_key=[0,42], [0, step])
    uint32_t fk0, fk1;
    threefry2x32(0u, 42u, 0u, (uint32_t)s, fk0, fk1);
    const float* xin = (s == 0) ? x : out;
    step_fused<<<NBLK, 256, 0, stream>>>(xin, W0, b0, W1, xn, alpha, mask, fk0, fk1);
    life_mask<<<NPIX / 256, 256, 0, stream>>>(xn, alpha, mask, out);
  }
}

// Round 3
// 234.843 us; speedup vs baseline: 1.6261x; 1.6261x over previous
//
#include <hip/hip_runtime.h>
#include <stdint.h>

// Problem constants: B=8, H=256, W=256, C=16, HID=128, steps=2
#define BB 8
#define HH 256
#define WW 256
#define CC 16
#define HID 128
#define NPIX (BB*HH*WW)     // 524288
#define MTILE 64            // pixels per block
#define NBLK (NPIX/MTILE)   // 8192

typedef _Float16 h8 __attribute__((ext_vector_type(8)));
typedef __fp16   fp16v2 __attribute__((ext_vector_type(2)));   // cvt_pkrtz return type
typedef float    f4 __attribute__((ext_vector_type(4)));

// ---- LDS layout (dwords). Ypk (perception, f16x2 hi/mid planes) unions with
// Hs (post-relu h, f32) — separated by barriers. Ctr/fire persist.
#define YPK_HI   0          // [64 px][52] u32 (48 kk pairs + pad): 3328 dw
#define YPK_MID  3328       // 3328..6655
#define HS_OFF   0          // [128 hid][68] f32 = 8704 dw (union, >= 6656)
#define CTR_OFF  8704       // [64 px][20] f32 = 1280 dw
#define FIRE_OFF 9984       // [64] f32
#define LDS_DW   10048      // 40192 B -> 4 blocks/CU

// ---------------- Threefry2x32 (JAX-compatible, 20 rounds) ----------------
__host__ __device__ __forceinline__ uint32_t rotl32(uint32_t x, int r) {
  return (x << r) | (x >> (32 - r));
}

__host__ __device__ inline void threefry2x32(uint32_t k0, uint32_t k1,
                                             uint32_t x0, uint32_t x1,
                                             uint32_t& o0, uint32_t& o1) {
  const uint32_t ks2 = k0 ^ k1 ^ 0x1BD11BDAu;
  x0 += k0; x1 += k1;
#define TF_R4(a,b,c,d) \
  x0 += x1; x1 = rotl32(x1,(a)); x1 ^= x0; \
  x0 += x1; x1 = rotl32(x1,(b)); x1 ^= x0; \
  x0 += x1; x1 = rotl32(x1,(c)); x1 ^= x0; \
  x0 += x1; x1 = rotl32(x1,(d)); x1 ^= x0;
  TF_R4(13,15,26,6)   x0 += k1;  x1 += ks2 + 1u;
  TF_R4(17,29,16,24)  x0 += ks2; x1 += k0 + 2u;
  TF_R4(13,15,26,6)   x0 += k0;  x1 += k1 + 3u;
  TF_R4(17,29,16,24)  x0 += k1;  x1 += ks2 + 4u;
  TF_R4(13,15,26,6)   x0 += ks2; x1 += k0 + 5u;
#undef TF_R4
  o0 = x0; o1 = x1;
}

// ---- split-fp16: a ~= hi + mid with |a-hi-mid| <= ~2^-21|a|.
// hi = RTN f16 (residual <= 2^-11|a|, exact f32 subtract), mid = RTZ of residual.
// 3-product MFMA (AhBh + AmBh + AhBm) error ~3*2^-21 rel -> alpha err ~1e-6,
// 10x inside the ~1e-5 life-threshold margin.
__device__ __forceinline__ void split2(float a, float b, uint32_t& hi, uint32_t& mid) {
  _Float16 ha = (_Float16)a, hb = (_Float16)b;       // v_cvt_f16_f32 (RTN)
  union { _Float16 h[2]; uint32_t u; } ph;
  ph.h[0] = ha; ph.h[1] = hb; hi = ph.u;
  float ra = a - (float)ha, rb = b - (float)hb;      // exact
  union { fp16v2 h; uint32_t u; } pu;
  pu.h = __builtin_amdgcn_cvt_pkrtz(ra, rb);         // v_cvt_pkrtz_f16_f32
  mid = pu.u;
}

// ---- W fragment precompute (once per launch; L2-resident afterwards) ------
// k-slot convention (shared by ALL A/B frags -> self-consistent, so the exact
// HW k-order is irrelevant): GEMM1 k = 32*ks + 8*g + 2*r + h.
// GEMM2 uses permuted khat = 2*g + 16*(r&1) + 8*h + (r>>1) to avoid a 4-way
// LDS bank g-collapse on the h reads (68*8g === 0 mod 32 otherwise).
__global__ __launch_bounds__(256)
void prep_frags(const float* __restrict__ W0g, const float* __restrict__ W1g,
                uint32_t* __restrict__ W0F, uint32_t* __restrict__ W1F) {
  const int tid = blockIdx.x * 256 + threadIdx.x;
  // W0F: [n=8][ks=3][term=2][lane=64][r=4]; value = split(W0[k][16n+c15]) (0 pad k>=80)
  for (int idx = tid; idx < 6144; idx += gridDim.x * 256) {
    const int r = idx & 3, l = (idx >> 2) & 63, ks = (idx >> 8) % 3, n = idx / 768;
    const int g = l >> 4, c = l & 15;
    const int k0 = 32 * ks + 8 * g + 2 * r;
    const int hid = 16 * n + c;
    const float a = (k0     < 80) ? W0g[k0 * HID + hid]       : 0.f;
    const float b = (k0 + 1 < 80) ? W0g[(k0 + 1) * HID + hid] : 0.f;
    uint32_t hi, mid; split2(a, b, hi, mid);
    W0F[(size_t)(((n * 3 + ks) * 2 + 0) * 64 + l) * 4 + r] = hi;
    W0F[(size_t)(((n * 3 + ks) * 2 + 1) * 64 + l) * 4 + r] = mid;
  }
  // W1F (A = W1^T): [ks=4][term=2][lane=64][r=4]; A[row=c15][k=hid], khat perm
  for (int idx = tid; idx < 1024; idx += gridDim.x * 256) {
    const int r = idx & 3, l = (idx >> 2) & 63, ks = idx >> 8;
    const int g = l >> 4, c = l & 15;
    float va[2];
#pragma unroll
    for (int h = 0; h < 2; ++h) {
      const int khat = 2 * g + 16 * (r & 1) + 8 * h + (r >> 1);
      va[h] = W1g[(size_t)(32 * ks + khat) * CC + c];
    }
    uint32_t hi, mid; split2(va[0], va[1], hi, mid);
    W1F[(size_t)((ks * 2 + 0) * 64 + l) * 4 + r] = hi;
    W1F[(size_t)((ks * 2 + 1) * 64 + l) * 4 + r] = mid;
  }
}

// ---------------- Fused step kernel (MFMA) ----------------
// 4 waves / 64-px tile. GEMM1: wave w owns hid-tiles {2w,2w+1} x all 4 px-tiles
// (K=80 pad 96, 72 mfma_16x16x32_f16). GEMM2 = W1^T @ h^T: wave w owns px-tile w
// (12 MFMAs); D: lane holds channels 4g..4g+3 of px=16w+c15 -> float4 stores.
__global__ __launch_bounds__(256, 4)
void step_fused(const float* __restrict__ xin,
                const uint32_t* __restrict__ W0F,
                const uint32_t* __restrict__ W1F,
                const float* __restrict__ b0g,
                float* __restrict__ xn,
                float* __restrict__ alpha_out,
                unsigned char* __restrict__ prelife,
                uint32_t k0, uint32_t k1) {
  __shared__ uint32_t LDSU[LDS_DW];
  float* const LDSF = (float*)LDSU;

  const int t    = threadIdx.x;
  const int blk  = blockIdx.x;
  const int lane = t & 63;
  const int w    = __builtin_amdgcn_readfirstlane(t >> 6);  // wave 0..3
  const int g    = lane >> 4;
  const int c15  = lane & 15;

  // -- phase 0: issue slab-0 B-frags + bias early (latency under perception) --
  uint4 BH[2][2], BM[2][2];           // [ks parity][nl]
#pragma unroll
  for (int nl = 0; nl < 2; ++nl) {
    const int n = 2 * w + nl;
    BH[0][nl] = *(const uint4*)(W0F + (size_t)(((n * 3 + 0) * 2 + 0) * 64 + lane) * 4);
    BM[0][nl] = *(const uint4*)(W0F + (size_t)(((n * 3 + 0) * 2 + 1) * 64 + lane) * 4);
  }
  const float bv0 = b0g[16 * (2 * w + 0) + c15];
  const float bv1 = b0g[16 * (2 * w + 1) + c15];

  // ---------------- perception: 4 channels per thread ----------------
  const int px  = t >> 2;
  const int c4  = (t & 3) * 4;
  const int gpx = blk * MTILE + px;
  const int bi  = gpx >> 16;
  const int ij  = gpx & 0xFFFF;
  const int ic  = ij >> 8;
  const int jc  = ij & 0xFF;

  const float DXW[3][3] = {{-0.125f, 0.0f, 0.125f},
                           {-0.25f,  0.0f, 0.25f },
                           {-0.125f, 0.0f, 0.125f}};
  const float DYW[3][3] = {{-0.125f, -0.25f, -0.125f},
                           { 0.0f,    0.0f,   0.0f  },
                           { 0.125f,  0.25f,  0.125f}};
  const float LPW[3][3] = {{0.125f, 0.25f, 0.125f},
                           {0.25f, -1.5f,  0.25f },
                           {0.125f, 0.25f, 0.125f}};
  const float L2W[3][3] = {{0.0f,   0.125f, 0.0f  },
                           {0.125f, -0.5f,  0.125f},
                           {0.0f,   0.125f, 0.0f  }};

  float ctr[4] = {0,0,0,0};
  float adx[4] = {0,0,0,0};
  float ady[4] = {0,0,0,0};
  float alp[4] = {0,0,0,0};
  float al2[4] = {0,0,0,0};
  float amax = 0.0f;

  const float* xb = xin + (size_t)bi * (HH * WW * CC);
#pragma unroll
  for (int di = -1; di <= 1; ++di) {
#pragma unroll
    for (int dj = -1; dj <= 1; ++dj) {
      const int ii = ic + di, jj = jc + dj;
      const bool ok = ((unsigned)ii < (unsigned)HH) && ((unsigned)jj < (unsigned)WW);
      float4 p = make_float4(0.f, 0.f, 0.f, 0.f);
      if (ok) p = *(const float4*)(xb + ((size_t)(ii * WW + jj) * CC + c4));
      const float wdx = DXW[di+1][dj+1], wdy = DYW[di+1][dj+1];
      const float wlp = LPW[di+1][dj+1], wl2 = L2W[di+1][dj+1];
      const float pv[4] = {p.x, p.y, p.z, p.w};
#pragma unroll
      for (int q = 0; q < 4; ++q) {
        if (di == 0 && dj == 0) ctr[q] = pv[q];
        if (wdx != 0.f) adx[q] = fmaf(pv[q], wdx, adx[q]);
        if (wdy != 0.f) ady[q] = fmaf(pv[q], wdy, ady[q]);
        if (wlp != 0.f) alp[q] = fmaf(pv[q], wlp, alp[q]);
        if (wl2 != 0.f) al2[q] = fmaf(pv[q], wl2, al2[q]);
      }
      if (c4 == 0) amax = fmaxf(amax, p.w);
    }
  }

  // Ypk writes: packed f16x2 pairs, kk = 8*grp + c4/2 (+1). stride 52: b64
  // writes land 4 dw/bank (minimal); b128 A-reads 8 dw/bank (minimal).
  {
    const int q2 = c4 >> 1;
#define WRYPK(grp, A) do { \
    uint32_t h0_, m0_, h1_, m1_; \
    split2(A[0], A[1], h0_, m0_); split2(A[2], A[3], h1_, m1_); \
    const int kk_ = 8 * (grp) + q2; \
    *(uint2*)&LDSU[YPK_HI  + px * 52 + kk_] = make_uint2(h0_, h1_); \
    *(uint2*)&LDSU[YPK_MID + px * 52 + kk_] = make_uint2(m0_, m1_); \
  } while (0)
    WRYPK(0, ctr); WRYPK(1, adx); WRYPK(2, ady); WRYPK(3, alp); WRYPK(4, al2);
#undef WRYPK
  }
  // zero K-pad rows kk 40..47 (k 80..95), both planes: 1024 dw / 256 threads
#pragma unroll
  for (int j = 0; j < 4; ++j) {
    const int pos = t * 4 + j;
    const int plane = pos >> 9, rem = pos & 511;
    LDSU[plane * 3328 + (rem >> 3) * 52 + 40 + (rem & 7)] = 0u;
  }
  // stash ctr (x-center) for epilogue; [64][20] pad -> bank-balanced b128
  *(f4*)&LDSU[CTR_OFF + px * 20 + c4] = (f4){ctr[0], ctr[1], ctr[2], ctr[3]};
  if (c4 == 0) prelife[gpx] = (amax > 0.1f) ? 1 : 0;
  // fire mask per pixel: wave 0, full 64 lanes
  if (t < 64) {
    uint32_t lo, hi2;
    threefry2x32(k0, k1, 0u, (uint32_t)(blk * MTILE + t), lo, hi2);
    const uint32_t bits = lo ^ hi2;
    const float u = __uint_as_float((bits >> 9) | 0x3f800000u) - 1.0f;
    LDSF[FIRE_OFF + t] = (u > 0.5f) ? 1.0f : 0.0f;
  }

  __syncthreads();

  // ------- GEMM1: D[px][hid] = Y @ W0, split-fp16 3-product MFMA ----------
  f4 C1[4][2];
#pragma unroll
  for (int m = 0; m < 4; ++m) {
    C1[m][0] = (f4){bv0, bv0, bv0, bv0};   // bias folded into acc init
    C1[m][1] = (f4){bv1, bv1, bv1, bv1};
  }

#define LOADB(par, kss) do { \
  _Pragma("unroll") for (int nl_ = 0; nl_ < 2; ++nl_) { \
    const int n_ = 2 * w + nl_; \
    BH[par][nl_] = *(const uint4*)(W0F + (size_t)(((n_ * 3 + (kss)) * 2 + 0) * 64 + lane) * 4); \
    BM[par][nl_] = *(const uint4*)(W0F + (size_t)(((n_ * 3 + (kss)) * 2 + 1) * 64 + lane) * 4); \
  } } while (0)

  const int abase = c15 * 52 + 4 * g;
#pragma unroll
  for (int ks = 0; ks < 3; ++ks) {
    if (ks == 0) LOADB(1, 1);
    if (ks == 1) LOADB(0, 2);
    const int cur = ks & 1;
#pragma unroll
    for (int m = 0; m < 4; ++m) {
      const uint4 uh = *(const uint4*)&LDSU[YPK_HI  + abase + m * 832 + 16 * ks];
      const uint4 um = *(const uint4*)&LDSU[YPK_MID + abase + m * 832 + 16 * ks];
      const h8 ah = __builtin_bit_cast(h8, uh);
      const h8 am = __builtin_bit_cast(h8, um);
#pragma unroll
      for (int nl = 0; nl < 2; ++nl) {
        const h8 bh = __builtin_bit_cast(h8, BH[cur][nl]);
        const h8 bm = __builtin_bit_cast(h8, BM[cur][nl]);
        C1[m][nl] = __builtin_amdgcn_mfma_f32_16x16x32_f16(ah, bh, C1[m][nl], 0, 0, 0);
        C1[m][nl] = __builtin_amdgcn_mfma_f32_16x16x32_f16(am, bh, C1[m][nl], 0, 0, 0);
        C1[m][nl] = __builtin_amdgcn_mfma_f32_16x16x32_f16(ah, bm, C1[m][nl], 0, 0, 0);
      }
    }
  }
#undef LOADB

  __syncthreads();   // all Ypk reads done before Hs overwrites the union

  // relu + h store: lane holds px rows {16m+4g..+3} at col hid -> b128 over px
#pragma unroll
  for (int m = 0; m < 4; ++m)
#pragma unroll
    for (int nl = 0; nl < 2; ++nl) {
      f4 hv = C1[m][nl];
      hv.x = fmaxf(hv.x, 0.f); hv.y = fmaxf(hv.y, 0.f);
      hv.z = fmaxf(hv.z, 0.f); hv.w = fmaxf(hv.w, 0.f);
      const int hid = 16 * (2 * w + nl) + c15;
      *(f4*)&LDSU[HS_OFF + hid * 68 + 16 * m + 4 * g] = hv;
    }

  // W1^T A-frags (latency covered by barrier + GEMM2 split work)
  uint4 W1H[4], W1M[4];
#pragma unroll
  for (int ks = 0; ks < 4; ++ks) {
    W1H[ks] = *(const uint4*)(W1F + (size_t)((ks * 2 + 0) * 64 + lane) * 4);
    W1M[ks] = *(const uint4*)(W1F + (size_t)((ks * 2 + 1) * 64 + lane) * 4);
  }

  __syncthreads();

  // ------- GEMM2: D[ch][px] = W1^T @ h^T (wave w: px-tile w) ---------------
  f4 C2 = (f4){0.f, 0.f, 0.f, 0.f};
  const int A2 = 136 * g + 16 * w + c15;   // 68*(2g) + px
#pragma unroll
  for (int ks = 0; ks < 4; ++ks) {
    uint32_t ph[4], pm[4];
#pragma unroll
    for (int r = 0; r < 4; ++r) {
      const int K0 = 16 * (r & 1) + (r >> 1);       // khat (h=0), minus 2g part
      const float a = LDSF[A2 + 68 * (32 * ks + K0)];
      const float b = LDSF[A2 + 68 * (32 * ks + K0 + 8)];
      split2(a, b, ph[r], pm[r]);
    }
    const uint4 uh = make_uint4(ph[0], ph[1], ph[2], ph[3]);
    const uint4 um = make_uint4(pm[0], pm[1], pm[2], pm[3]);
    const h8 bh = __builtin_bit_cast(h8, uh);
    const h8 bm = __builtin_bit_cast(h8, um);
    const h8 ah = __builtin_bit_cast(h8, W1H[ks]);
    const h8 am = __builtin_bit_cast(h8, W1M[ks]);
    C2 = __builtin_amdgcn_mfma_f32_16x16x32_f16(ah, bh, C2, 0, 0, 0);
    C2 = __builtin_amdgcn_mfma_f32_16x16x32_f16(am, bh, C2, 0, 0, 0);
    C2 = __builtin_amdgcn_mfma_f32_16x16x32_f16(ah, bm, C2, 0, 0, 0);
  }

  // ------- epilogue: x + d*fire, coalesced float4 store --------------------
  // lane holds channels 4g..4g+3 (regs) of pixel pxt = 16w + c15
  {
    const int pxt  = 16 * w + c15;
    const int gpx2 = blk * MTILE + pxt;
    const f4 ctr4 = *(const f4*)&LDSU[CTR_OFF + pxt * 20 + 4 * g];
    const float fire01 = LDSF[FIRE_OFF + pxt];
    f4 xv;
    xv.x = fmaf(C2.x, fire01, ctr4.x);
    xv.y = fmaf(C2.y, fire01, ctr4.y);
    xv.z = fmaf(C2.z, fire01, ctr4.z);
    xv.w = fmaf(C2.w, fire01, ctr4.w);
    *(f4*)&xn[(size_t)gpx2 * CC + 4 * g] = xv;
    if (g == 0) alpha_out[gpx2] = xv.w;   // channel 3
  }
}

// ---------------- Kernel B: life mask ----------------
__global__ __launch_bounds__(256)
void life_mask(const float* __restrict__ xn,
               const float* __restrict__ alpha,
               const unsigned char* __restrict__ prelife,
               float* __restrict__ out) {
  const int idx = blockIdx.x * 256 + threadIdx.x;
  const int b  = idx >> 16;
  const int ij = idx & 0xFFFF;
  const int i  = ij >> 8;
  const int j  = ij & 0xFF;

  const float* ab = alpha + (size_t)b * (HH * WW);
  float amax = 0.0f;
#pragma unroll
  for (int di = -1; di <= 1; ++di) {
    const int ii = i + di;
    if ((unsigned)ii >= (unsigned)HH) continue;
#pragma unroll
    for (int dj = -1; dj <= 1; ++dj) {
      const int jj = j + dj;
      if ((unsigned)jj >= (unsigned)WW) continue;
      amax = fmaxf(amax, ab[(size_t)ii * WW + jj]);
    }
  }
  const bool life = (prelife[idx] != 0) && (amax > 0.1f);

  const float4* src = (const float4*)(xn + (size_t)idx * CC);
  float4* dst = (float4*)(out + (size_t)idx * CC);
  if (life) {
    dst[0] = src[0]; dst[1] = src[1]; dst[2] = src[2]; dst[3] = src[3];
  } else {
    const float4 z = make_float4(0.0f, 0.0f, 0.0f, 0.0f);
    dst[0] = z; dst[1] = z; dst[2] = z; dst[3] = z;
  }
}

// ---------------- Host launcher ----------------
extern "C" void kernel_launch(void* const* d_in, const int* in_sizes, int n_in,
                              void* d_out, int out_size, void* d_ws, size_t ws_size,
                              hipStream_t stream) {
  (void)in_sizes; (void)n_in; (void)out_size; (void)ws_size;
  const float* x  = (const float*)d_in[0];
  const float* W0 = (const float*)d_in[1];
  const float* b0 = (const float*)d_in[2];
  const float* W1 = (const float*)d_in[3];
  float* out = (float*)d_out;

  // Workspace: xn (32MB) | alpha (2MB) | prelife (0.5MB) | W0F (48KB) | W1F (8KB)
  float* xn = (float*)d_ws;
  float* alpha = xn + (size_t)NPIX * CC;
  unsigned char* mask = (unsigned char*)(alpha + NPIX);
  uint32_t* W0F = (uint32_t*)(mask + NPIX);
  uint32_t* W1F = W0F + 12288;

  prep_frags<<<24, 256, 0, stream>>>(W0, W1, W0F, W1F);

  const int steps = 2;
  for (int s = 0; s < steps; ++s) {
    uint32_t fk0, fk1;
    threefry2x32(0u, 42u, 0u, (uint32_t)s, fk0, fk1);
    const float* xin = (s == 0) ? x : out;
    step_fused<<<NBLK, 256, 0, stream>>>(xin, W0F, W1F, b0, xn, alpha, mask, fk0, fk1);
    life_mask<<<NPIX / 256, 256, 0, stream>>>(xn, alpha, mask, out);
  }
}

// Round 4
// 217.409 us; speedup vs baseline: 1.7565x; 1.0802x over previous
//
#include <hip/hip_runtime.h>
#include <stdint.h>

// Problem constants: B=8, H=256, W=256, C=16, HID=128, steps=2
#define BB 8
#define HH 256
#define WW 256
#define CC 16
#define HID 128
#define NPIX (BB*HH*WW)     // 524288
#define MTILE 64            // pixels per block
#define NBLK (NPIX/MTILE)   // 8192

typedef _Float16 h8 __attribute__((ext_vector_type(8)));
typedef __fp16   fp16v2 __attribute__((ext_vector_type(2)));   // cvt_pkrtz return type
typedef float    f4 __attribute__((ext_vector_type(4)));

// ---- LDS layout (dwords). Ypk (perception, f16x2 hi/mid planes) unions with
// Hs (post-relu h, f32) — separated by barriers. Ctr/fire persist.
// Alpha-halo + life planes live in the hole [6656..8703] that Ypk doesn't use
// and Hs only clobbers after GEMM1 (when life is dead).
#define YPK_HI     0        // [64 px][52] u32 (48 kk pairs + pad): 3328 dw
#define YPK_MID    3328     // 3328..6655
#define HS_OFF     0        // [128 hid][68] f32 = 8704 dw (union)
#define ALPHA5_OFF 6656     // [5][68] f32 alpha halo = 340 dw (6656..6995)
#define LIFE_OFF   6996     // [3][66] f32 life plane = 198 dw (6996..7193)
#define CTR_OFF    8704     // [64 px][20] f32 = 1280 dw
#define FIRE_OFF   9984     // [64] f32
#define LDS_DW     10048    // 40192 B -> 4 blocks/CU

// ---------------- Threefry2x32 (JAX-compatible, 20 rounds) ----------------
__host__ __device__ __forceinline__ uint32_t rotl32(uint32_t x, int r) {
  return (x << r) | (x >> (32 - r));
}

__host__ __device__ inline void threefry2x32(uint32_t k0, uint32_t k1,
                                             uint32_t x0, uint32_t x1,
                                             uint32_t& o0, uint32_t& o1) {
  const uint32_t ks2 = k0 ^ k1 ^ 0x1BD11BDAu;
  x0 += k0; x1 += k1;
#define TF_R4(a,b,c,d) \
  x0 += x1; x1 = rotl32(x1,(a)); x1 ^= x0; \
  x0 += x1; x1 = rotl32(x1,(b)); x1 ^= x0; \
  x0 += x1; x1 = rotl32(x1,(c)); x1 ^= x0; \
  x0 += x1; x1 = rotl32(x1,(d)); x1 ^= x0;
  TF_R4(13,15,26,6)   x0 += k1;  x1 += ks2 + 1u;
  TF_R4(17,29,16,24)  x0 += ks2; x1 += k0 + 2u;
  TF_R4(13,15,26,6)   x0 += k0;  x1 += k1 + 3u;
  TF_R4(17,29,16,24)  x0 += k1;  x1 += ks2 + 4u;
  TF_R4(13,15,26,6)   x0 += ks2; x1 += k0 + 5u;
#undef TF_R4
  o0 = x0; o1 = x1;
}

// ---- split-fp16: a ~= hi + mid with |a-hi-mid| <= ~2^-21|a|.
__device__ __forceinline__ void split2(float a, float b, uint32_t& hi, uint32_t& mid) {
  _Float16 ha = (_Float16)a, hb = (_Float16)b;       // v_cvt_f16_f32 (RTN)
  union { _Float16 h[2]; uint32_t u; } ph;
  ph.h[0] = ha; ph.h[1] = hb; hi = ph.u;
  float ra = a - (float)ha, rb = b - (float)hb;      // exact
  union { fp16v2 h; uint32_t u; } pu;
  pu.h = __builtin_amdgcn_cvt_pkrtz(ra, rb);         // v_cvt_pkrtz_f16_f32
  mid = pu.u;
}

// ---- W fragment precompute (once per launch; L2-resident afterwards) ------
// k-slot convention: GEMM1 k = 32*ks + 8*g + 2*r + h.
// GEMM2 khat = 2*g + 16*(r&1) + 8*h + (r>>1) (kills LDS g-collapse on h reads).
__global__ __launch_bounds__(256)
void prep_frags(const float* __restrict__ W0g, const float* __restrict__ W1g,
                uint32_t* __restrict__ W0F, uint32_t* __restrict__ W1F) {
  const int tid = blockIdx.x * 256 + threadIdx.x;
  for (int idx = tid; idx < 6144; idx += gridDim.x * 256) {
    const int r = idx & 3, l = (idx >> 2) & 63, ks = (idx >> 8) % 3, n = idx / 768;
    const int g = l >> 4, c = l & 15;
    const int k0 = 32 * ks + 8 * g + 2 * r;
    const int hid = 16 * n + c;
    const float a = (k0     < 80) ? W0g[k0 * HID + hid]       : 0.f;
    const float b = (k0 + 1 < 80) ? W0g[(k0 + 1) * HID + hid] : 0.f;
    uint32_t hi, mid; split2(a, b, hi, mid);
    W0F[(size_t)(((n * 3 + ks) * 2 + 0) * 64 + l) * 4 + r] = hi;
    W0F[(size_t)(((n * 3 + ks) * 2 + 1) * 64 + l) * 4 + r] = mid;
  }
  for (int idx = tid; idx < 1024; idx += gridDim.x * 256) {
    const int r = idx & 3, l = (idx >> 2) & 63, ks = idx >> 8;
    const int g = l >> 4, c = l & 15;
    float va[2];
#pragma unroll
    for (int h = 0; h < 2; ++h) {
      const int khat = 2 * g + 16 * (r & 1) + 8 * h + (r >> 1);
      va[h] = W1g[(size_t)(32 * ks + khat) * CC + c];
    }
    uint32_t hi, mid; split2(va[0], va[1], hi, mid);
    W1F[(size_t)((ks * 2 + 0) * 64 + l) * 4 + r] = hi;
    W1F[(size_t)((ks * 2 + 1) * 64 + l) * 4 + r] = mid;
  }
}

// ---------------- Fused step kernel (MFMA) ----------------
// apply_life=1: inputs are UNMASKED previous-step xn; the previous step's life
// mask (maskPrev & max3x3(alphaPrev)>0.1) is computed per-block into LDS and
// applied to every perception tap (exact 1.0/0.0 multiply — bit-identical to
// reading a pre-masked buffer; saves an entire 64MB-traffic masking dispatch).
__global__ __launch_bounds__(256, 4)
void step_fused(const float* __restrict__ xin,
                const uint32_t* __restrict__ W0F,
                const uint32_t* __restrict__ W1F,
                const float* __restrict__ b0g,
                const float* __restrict__ aPrev,
                const unsigned char* __restrict__ mPrev,
                float* __restrict__ xn,
                float* __restrict__ alpha_out,
                unsigned char* __restrict__ prelife,
                uint32_t k0, uint32_t k1, int apply_life) {
  __shared__ uint32_t LDSU[LDS_DW];
  float* const LDSF = (float*)LDSU;

  const int t    = threadIdx.x;
  const int blk  = blockIdx.x;
  const int lane = t & 63;
  const int w    = __builtin_amdgcn_readfirstlane(t >> 6);  // wave 0..3
  const int g    = lane >> 4;
  const int c15  = lane & 15;

  // -- phase 0: issue slab-0 B-frags + bias early (latency under perception) --
  uint4 BH[2][2], BM[2][2];           // [ks parity][nl]
#pragma unroll
  for (int nl = 0; nl < 2; ++nl) {
    const int n = 2 * w + nl;
    BH[0][nl] = *(const uint4*)(W0F + (size_t)(((n * 3 + 0) * 2 + 0) * 64 + lane) * 4);
    BM[0][nl] = *(const uint4*)(W0F + (size_t)(((n * 3 + 0) * 2 + 1) * 64 + lane) * 4);
  }
  const float bv0 = b0g[16 * (2 * w + 0) + c15];
  const float bv1 = b0g[16 * (2 * w + 1) + c15];

  // Block geometry: 64 consecutive pixels = one row segment (never crosses rows)
  const int base_ = blk * MTILE;
  const int bi    = base_ >> 16;
  const int rc    = base_ & 0xFFFF;
  const int ic    = rc >> 8;
  const int jc0   = rc & 0xFF;        // multiple of 64

  // ---- inline life of previous step (apply_life only) ----
  if (apply_life) {
    const float* ap = aPrev + (size_t)bi * (HH * WW);
    for (int it = t; it < 340; it += 256) {        // alpha halo 5 x 68
      const int r = it / 68, c = it - r * 68;
      const int ii = ic - 2 + r, jj = jc0 - 2 + c;
      float v = 0.f;
      if ((unsigned)ii < (unsigned)HH && (unsigned)jj < (unsigned)WW)
        v = ap[ii * WW + jj];
      LDSF[ALPHA5_OFF + it] = v;
    }
    __syncthreads();
    if (t < 198) {                                  // life plane 3 x 66
      const int r = t / 66, xx = t - r * 66;
      const float* a0 = &LDSF[ALPHA5_OFF + r * 68 + xx];
      const float m0 = fmaxf(fmaxf(a0[0],   a0[1]),   a0[2]);
      const float m1 = fmaxf(fmaxf(a0[68],  a0[69]),  a0[70]);
      const float m2 = fmaxf(fmaxf(a0[136], a0[137]), a0[138]);
      const float mm = fmaxf(fmaxf(m0, m1), m2);
      const int ii = ic - 1 + r, jj = jc0 - 1 + xx;
      int pl = 0;
      if ((unsigned)ii < (unsigned)HH && (unsigned)jj < (unsigned)WW)
        pl = mPrev[(size_t)bi * (HH * WW) + ii * WW + jj];
      LDSF[LIFE_OFF + t] = (pl && mm > 0.1f) ? 1.0f : 0.0f;
    }
    __syncthreads();
  }

  // ---------------- perception: 4 channels per thread ----------------
  const int px  = t >> 2;
  const int c4  = (t & 3) * 4;
  const int gpx = base_ + px;
  const int jc  = jc0 + px;

  const float DXW[3][3] = {{-0.125f, 0.0f, 0.125f},
                           {-0.25f,  0.0f, 0.25f },
                           {-0.125f, 0.0f, 0.125f}};
  const float DYW[3][3] = {{-0.125f, -0.25f, -0.125f},
                           { 0.0f,    0.0f,   0.0f  },
                           { 0.125f,  0.25f,  0.125f}};
  const float LPW[3][3] = {{0.125f, 0.25f, 0.125f},
                           {0.25f, -1.5f,  0.25f },
                           {0.125f, 0.25f, 0.125f}};
  const float L2W[3][3] = {{0.0f,   0.125f, 0.0f  },
                           {0.125f, -0.5f,  0.125f},
                           {0.0f,   0.125f, 0.0f  }};

  float ctr[4] = {0,0,0,0};
  float adx[4] = {0,0,0,0};
  float ady[4] = {0,0,0,0};
  float alp[4] = {0,0,0,0};
  float al2[4] = {0,0,0,0};
  float amax = 0.0f;

  const float* xb = xin + (size_t)bi * (HH * WW * CC);
#pragma unroll
  for (int di = -1; di <= 1; ++di) {
#pragma unroll
    for (int dj = -1; dj <= 1; ++dj) {
      const int ii = ic + di, jj = jc + dj;
      const bool ok = ((unsigned)ii < (unsigned)HH) && ((unsigned)jj < (unsigned)WW);
      float4 p = make_float4(0.f, 0.f, 0.f, 0.f);
      if (ok) p = *(const float4*)(xb + ((size_t)(ii * WW + jj) * CC + c4));
      if (apply_life) {
        const float lf = LDSF[LIFE_OFF + (di + 1) * 66 + (px + dj + 1)];
        p.x *= lf; p.y *= lf; p.z *= lf; p.w *= lf;
      }
      const float wdx = DXW[di+1][dj+1], wdy = DYW[di+1][dj+1];
      const float wlp = LPW[di+1][dj+1], wl2 = L2W[di+1][dj+1];
      const float pv[4] = {p.x, p.y, p.z, p.w};
#pragma unroll
      for (int q = 0; q < 4; ++q) {
        if (di == 0 && dj == 0) ctr[q] = pv[q];
        if (wdx != 0.f) adx[q] = fmaf(pv[q], wdx, adx[q]);
        if (wdy != 0.f) ady[q] = fmaf(pv[q], wdy, ady[q]);
        if (wlp != 0.f) alp[q] = fmaf(pv[q], wlp, alp[q]);
        if (wl2 != 0.f) al2[q] = fmaf(pv[q], wl2, al2[q]);
      }
      if (c4 == 0) amax = fmaxf(amax, p.w);
    }
  }

  // Ypk writes: packed f16x2 pairs, kk = 8*grp + c4/2 (+1). stride 52.
  {
    const int q2 = c4 >> 1;
#define WRYPK(grp, A) do { \
    uint32_t h0_, m0_, h1_, m1_; \
    split2(A[0], A[1], h0_, m0_); split2(A[2], A[3], h1_, m1_); \
    const int kk_ = 8 * (grp) + q2; \
    *(uint2*)&LDSU[YPK_HI  + px * 52 + kk_] = make_uint2(h0_, h1_); \
    *(uint2*)&LDSU[YPK_MID + px * 52 + kk_] = make_uint2(m0_, m1_); \
  } while (0)
    WRYPK(0, ctr); WRYPK(1, adx); WRYPK(2, ady); WRYPK(3, alp); WRYPK(4, al2);
#undef WRYPK
  }
  // zero K-pad rows kk 40..47 (k 80..95), both planes
#pragma unroll
  for (int j = 0; j < 4; ++j) {
    const int pos = t * 4 + j;
    const int plane = pos >> 9, rem = pos & 511;
    LDSU[plane * 3328 + (rem >> 3) * 52 + 40 + (rem & 7)] = 0u;
  }
  // stash ctr (masked center x) for epilogue
  *(f4*)&LDSU[CTR_OFF + px * 20 + c4] = (f4){ctr[0], ctr[1], ctr[2], ctr[3]};
  if (c4 == 0) prelife[gpx] = (amax > 0.1f) ? 1 : 0;
  // fire mask per pixel: wave 0, full 64 lanes
  if (t < 64) {
    uint32_t lo, hi2;
    threefry2x32(k0, k1, 0u, (uint32_t)(base_ + t), lo, hi2);
    const uint32_t bits = lo ^ hi2;
    const float u = __uint_as_float((bits >> 9) | 0x3f800000u) - 1.0f;
    LDSF[FIRE_OFF + t] = (u > 0.5f) ? 1.0f : 0.0f;
  }

  __syncthreads();

  // ------- GEMM1: D[px][hid] = Y @ W0, split-fp16 3-product MFMA ----------
  f4 C1[4][2];
#pragma unroll
  for (int m = 0; m < 4; ++m) {
    C1[m][0] = (f4){bv0, bv0, bv0, bv0};
    C1[m][1] = (f4){bv1, bv1, bv1, bv1};
  }

#define LOADB(par, kss) do { \
  _Pragma("unroll") for (int nl_ = 0; nl_ < 2; ++nl_) { \
    const int n_ = 2 * w + nl_; \
    BH[par][nl_] = *(const uint4*)(W0F + (size_t)(((n_ * 3 + (kss)) * 2 + 0) * 64 + lane) * 4); \
    BM[par][nl_] = *(const uint4*)(W0F + (size_t)(((n_ * 3 + (kss)) * 2 + 1) * 64 + lane) * 4); \
  } } while (0)

  const int abase = c15 * 52 + 4 * g;
#pragma unroll
  for (int ks = 0; ks < 3; ++ks) {
    if (ks == 0) LOADB(1, 1);
    if (ks == 1) LOADB(0, 2);
    const int cur = ks & 1;
#pragma unroll
    for (int m = 0; m < 4; ++m) {
      const uint4 uh = *(const uint4*)&LDSU[YPK_HI  + abase + m * 832 + 16 * ks];
      const uint4 um = *(const uint4*)&LDSU[YPK_MID + abase + m * 832 + 16 * ks];
      const h8 ah = __builtin_bit_cast(h8, uh);
      const h8 am = __builtin_bit_cast(h8, um);
#pragma unroll
      for (int nl = 0; nl < 2; ++nl) {
        const h8 bh = __builtin_bit_cast(h8, BH[cur][nl]);
        const h8 bm = __builtin_bit_cast(h8, BM[cur][nl]);
        C1[m][nl] = __builtin_amdgcn_mfma_f32_16x16x32_f16(ah, bh, C1[m][nl], 0, 0, 0);
        C1[m][nl] = __builtin_amdgcn_mfma_f32_16x16x32_f16(am, bh, C1[m][nl], 0, 0, 0);
        C1[m][nl] = __builtin_amdgcn_mfma_f32_16x16x32_f16(ah, bm, C1[m][nl], 0, 0, 0);
      }
    }
  }
#undef LOADB

  __syncthreads();   // all Ypk reads done before Hs overwrites the union

  // relu + h store
#pragma unroll
  for (int m = 0; m < 4; ++m)
#pragma unroll
    for (int nl = 0; nl < 2; ++nl) {
      f4 hv = C1[m][nl];
      hv.x = fmaxf(hv.x, 0.f); hv.y = fmaxf(hv.y, 0.f);
      hv.z = fmaxf(hv.z, 0.f); hv.w = fmaxf(hv.w, 0.f);
      const int hid = 16 * (2 * w + nl) + c15;
      *(f4*)&LDSU[HS_OFF + hid * 68 + 16 * m + 4 * g] = hv;
    }

  // W1^T A-frags
  uint4 W1H[4], W1M[4];
#pragma unroll
  for (int ks = 0; ks < 4; ++ks) {
    W1H[ks] = *(const uint4*)(W1F + (size_t)((ks * 2 + 0) * 64 + lane) * 4);
    W1M[ks] = *(const uint4*)(W1F + (size_t)((ks * 2 + 1) * 64 + lane) * 4);
  }

  __syncthreads();

  // ------- GEMM2: D[ch][px] = W1^T @ h^T (wave w: px-tile w) ---------------
  f4 C2 = (f4){0.f, 0.f, 0.f, 0.f};
  const int A2 = 136 * g + 16 * w + c15;
#pragma unroll
  for (int ks = 0; ks < 4; ++ks) {
    uint32_t ph[4], pm[4];
#pragma unroll
    for (int r = 0; r < 4; ++r) {
      const int K0 = 16 * (r & 1) + (r >> 1);
      const float a = LDSF[A2 + 68 * (32 * ks + K0)];
      const float b = LDSF[A2 + 68 * (32 * ks + K0 + 8)];
      split2(a, b, ph[r], pm[r]);
    }
    const uint4 uh = make_uint4(ph[0], ph[1], ph[2], ph[3]);
    const uint4 um = make_uint4(pm[0], pm[1], pm[2], pm[3]);
    const h8 bh = __builtin_bit_cast(h8, uh);
    const h8 bm = __builtin_bit_cast(h8, um);
    const h8 ah = __builtin_bit_cast(h8, W1H[ks]);
    const h8 am = __builtin_bit_cast(h8, W1M[ks]);
    C2 = __builtin_amdgcn_mfma_f32_16x16x32_f16(ah, bh, C2, 0, 0, 0);
    C2 = __builtin_amdgcn_mfma_f32_16x16x32_f16(am, bh, C2, 0, 0, 0);
    C2 = __builtin_amdgcn_mfma_f32_16x16x32_f16(ah, bm, C2, 0, 0, 0);
  }

  // ------- epilogue: x + d*fire, coalesced float4 store --------------------
  {
    const int pxt  = 16 * w + c15;
    const int gpx2 = base_ + pxt;
    const f4 ctr4 = *(const f4*)&LDSU[CTR_OFF + pxt * 20 + 4 * g];
    const float fire01 = LDSF[FIRE_OFF + pxt];
    f4 xv;
    xv.x = fmaf(C2.x, fire01, ctr4.x);
    xv.y = fmaf(C2.y, fire01, ctr4.y);
    xv.z = fmaf(C2.z, fire01, ctr4.z);
    xv.w = fmaf(C2.w, fire01, ctr4.w);
    *(f4*)&xn[(size_t)gpx2 * CC + 4 * g] = xv;
    if (g == 0) alpha_out[gpx2] = xv.w;   // channel 3
  }
}

// ---------------- Kernel B: final life mask, write-only-dead, in-place -----
// Live pixels (the overwhelming majority) are already correct in `out`; only
// dead pixels get 64B of zeros. Traffic: ~2.5MB reads + tiny writes.
__global__ __launch_bounds__(256)
void life_final(float* __restrict__ out,
                const float* __restrict__ alpha,
                const unsigned char* __restrict__ prelife) {
  const int idx = blockIdx.x * 256 + threadIdx.x;
  const int b  = idx >> 16;
  const int ij = idx & 0xFFFF;
  const int i  = ij >> 8;
  const int j  = ij & 0xFF;

  const float* ab = alpha + (size_t)b * (HH * WW);
  float amax = 0.0f;
#pragma unroll
  for (int di = -1; di <= 1; ++di) {
    const int ii = i + di;
    if ((unsigned)ii >= (unsigned)HH) continue;
#pragma unroll
    for (int dj = -1; dj <= 1; ++dj) {
      const int jj = j + dj;
      if ((unsigned)jj >= (unsigned)WW) continue;
      amax = fmaxf(amax, ab[(size_t)ii * WW + jj]);
    }
  }
  const bool life = (prelife[idx] != 0) && (amax > 0.1f);
  if (!life) {
    const float4 z = make_float4(0.0f, 0.0f, 0.0f, 0.0f);
    float4* dst = (float4*)(out + (size_t)idx * CC);
    dst[0] = z; dst[1] = z; dst[2] = z; dst[3] = z;
  }
}

// ---------------- Host launcher ----------------
extern "C" void kernel_launch(void* const* d_in, const int* in_sizes, int n_in,
                              void* d_out, int out_size, void* d_ws, size_t ws_size,
                              hipStream_t stream) {
  (void)in_sizes; (void)n_in; (void)out_size; (void)ws_size;
  const float* x  = (const float*)d_in[0];
  const float* W0 = (const float*)d_in[1];
  const float* b0 = (const float*)d_in[2];
  const float* W1 = (const float*)d_in[3];
  float* out = (float*)d_out;

  // Workspace: xn (32MB) | alphaA (2MB) | alphaB (2MB) | maskA (0.5MB) |
  //            maskB (0.5MB) | W0F (48KB) | W1F (8KB)   (~37.1MB)
  float* xn = (float*)d_ws;
  float* alphaA = xn + (size_t)NPIX * CC;
  float* alphaB = alphaA + NPIX;
  unsigned char* maskA = (unsigned char*)(alphaB + NPIX);
  unsigned char* maskB = maskA + NPIX;
  uint32_t* W0F = (uint32_t*)(maskB + NPIX);
  uint32_t* W1F = W0F + 12288;

  prep_frags<<<24, 256, 0, stream>>>(W0, W1, W0F, W1F);

  uint32_t fk0, fk1;
  // step 0: raw input (no life), unmasked result -> xn, alpha/mask -> A
  threefry2x32(0u, 42u, 0u, 0u, fk0, fk1);
  step_fused<<<NBLK, 256, 0, stream>>>(x, W0F, W1F, b0, alphaA, maskA,
                                       xn, alphaA, maskA, fk0, fk1, 0);
  // step 1: reads UNMASKED xn, applies step-0 life inline (alphaA/maskA),
  // unmasked result -> out, alpha/mask -> B
  threefry2x32(0u, 42u, 0u, 1u, fk0, fk1);
  step_fused<<<NBLK, 256, 0, stream>>>(xn, W0F, W1F, b0, alphaA, maskA,
                                       out, alphaB, maskB, fk0, fk1, 1);
  // final masking: zero dead pixels of out in place
  life_final<<<NPIX / 256, 256, 0, stream>>>(out, alphaB, maskB);
}